// Round 2
// baseline (5519.280 us; speedup 1.0000x reference)
//
#include <hip/hip_runtime.h>
#include <math.h>

// Problem constants
#define BDIM 4096
#define NEXP 8
#define HDIM 1024
#define XDIM 800
#define ZDIM 64
#define ODIM 768
#define GH   128

typedef _Float16 f16;
typedef f16   f16x8 __attribute__((ext_vector_type(8)));
typedef f16   f16x4 __attribute__((ext_vector_type(4)));
typedef float f32x4 __attribute__((ext_vector_type(4)));

__device__ __forceinline__ float elu_act(float x) {
    return x > 0.0f ? x : expm1f(x);
}

// async global->LDS, 16B per lane; LDS dest is wave-uniform base + lane*16
__device__ __forceinline__ void glds16(const void* g, void* l) {
    __builtin_amdgcn_global_load_lds(
        (const __attribute__((address_space(1))) void*)g,
        (__attribute__((address_space(3))) void*)l, 16, 0, 0);
}

__device__ __forceinline__ f16x8 vscale(f16x8 v, f16 s) {
    f16x8 r;
    #pragma unroll
    for (int i = 0; i < 8; ++i) r[i] = v[i] * s;
    return r;
}

// ===========================================================================
// fp32 tiled GEMM with implicit concat input (gating MLP only — small)
// ===========================================================================
#define BMg 64
#define BNg 64
#define BKg 32
#define PADg 68

template<int ACT>
__global__ __launch_bounds__(256)
void gemm_cat(const float* __restrict__ srcA, int KH,
              const float* __restrict__ srcZ, int KZ,
              const float* __restrict__ W, const float* __restrict__ bias,
              float* __restrict__ dst, int N)
{
    __shared__ float lds_a[BKg][PADg];
    __shared__ float lds_b[BKg][PADg];
    const int K = KH + KZ;
    const int row0 = blockIdx.x * BMg;
    const int col0 = blockIdx.y * BNg;
    const int tid = threadIdx.x;
    const int tx = tid & 15, ty = tid >> 4;

    float acc[4][4] = {};

    for (int k0 = 0; k0 < K; k0 += BKg) {
        #pragma unroll
        for (int it = 0; it < 2; ++it) {
            int idx = tid + it * 256;
            int r = idx >> 3;
            int f = idx & 7;
            int k = k0 + f * 4;
            const float* src; int col;
            if (k < KH) { src = srcA + (size_t)(row0 + r) * KH; col = k; }
            else        { src = srcZ + (size_t)(row0 + r) * KZ; col = k - KH; }
            float4 v = *(const float4*)(src + col);
            lds_a[f*4+0][r] = v.x; lds_a[f*4+1][r] = v.y;
            lds_a[f*4+2][r] = v.z; lds_a[f*4+3][r] = v.w;
        }
        #pragma unroll
        for (int it = 0; it < 2; ++it) {
            int idx = tid + it * 256;
            int c = idx >> 3;
            int f = idx & 7;
            int k = k0 + f * 4;
            float4 v = *(const float4*)(W + (size_t)(col0 + c) * K + k);
            lds_b[f*4+0][c] = v.x; lds_b[f*4+1][c] = v.y;
            lds_b[f*4+2][c] = v.z; lds_b[f*4+3][c] = v.w;
        }
        __syncthreads();
        #pragma unroll
        for (int j = 0; j < BKg; ++j) {
            float4 a4 = *(const float4*)&lds_a[j][ty*4];
            float4 b4 = *(const float4*)&lds_b[j][tx*4];
            float a[4] = {a4.x, a4.y, a4.z, a4.w};
            float b[4] = {b4.x, b4.y, b4.z, b4.w};
            #pragma unroll
            for (int i = 0; i < 4; ++i)
                #pragma unroll
                for (int jj = 0; jj < 4; ++jj)
                    acc[i][jj] += a[i] * b[jj];
        }
        __syncthreads();
    }

    #pragma unroll
    for (int i = 0; i < 4; ++i) {
        int r = row0 + ty*4 + i;
        float vals[4];
        #pragma unroll
        for (int j = 0; j < 4; ++j) {
            float v = acc[i][j] + bias[col0 + tx*4 + j];
            vals[j] = (ACT == 1) ? elu_act(v) : v;
        }
        *(float4*)(dst + (size_t)r * N + col0 + tx*4) =
            make_float4(vals[0], vals[1], vals[2], vals[3]);
    }
}

// ===========================================================================
// Gating layer 3 + softmax (fp32)
// ===========================================================================
__global__ __launch_bounds__(256)
void gating3_softmax(const float* __restrict__ g2, const float* __restrict__ Wg3,
                     const float* __restrict__ bg3, float* __restrict__ bc)
{
    __shared__ float w[NEXP * GH];
    __shared__ float bsh[NEXP];
    const int tid = threadIdx.x;
    for (int i = tid; i < NEXP * GH; i += 256) w[i] = Wg3[i];
    if (tid < NEXP) bsh[tid] = bg3[tid];
    __syncthreads();

    const int rowl = tid >> 3;
    const int o    = tid & 7;
    const int row  = blockIdx.x * 32 + rowl;
    const float* g = g2 + (size_t)row * GH;

    float s = bsh[o];
    for (int k = 0; k < GH; ++k) s += g[k] * w[o * GH + k];

    float m = s;
    #pragma unroll
    for (int d = 4; d >= 1; d >>= 1) m = fmaxf(m, __shfl_xor(m, d, 8));
    float e = expf(s - m);
    float sum = e;
    #pragma unroll
    for (int d = 4; d >= 1; d >>= 1) sum += __shfl_xor(sum, d, 8);

    bc[(size_t)blockIdx.x * 256 + tid] = e / sum;
}

// ===========================================================================
// Helper kernels
// ===========================================================================
// Fill z-columns (1024..1087) of both hz buffers with f16(z) (unscaled).
__global__ __launch_bounds__(256)
void fill_z(const float* __restrict__ z, f16* __restrict__ hz_a,
            f16* __restrict__ hz_b)
{
    int i = (blockIdx.x * 256 + threadIdx.x) * 4;      // over 4096*64
    int row = i >> 6;
    int col = i & 63;
    float4 v = *(const float4*)(z + i);
    f16x4 o = { (f16)v.x, (f16)v.y, (f16)v.z, (f16)v.w };
    size_t off = (size_t)row * (HDIM + ZDIM) + HDIM + col;
    *(f16x4*)(hz_a + off) = o;
    *(f16x4*)(hz_b + off) = o;
}

// fp32 -> f16 weight conversion, 8 elements/thread
__global__ __launch_bounds__(256)
void w_to_f16(const float* __restrict__ src, f16* __restrict__ dst)
{
    size_t i = ((size_t)blockIdx.x * 256 + threadIdx.x) * 8;
    float4 v0 = *(const float4*)(src + i);
    float4 v1 = *(const float4*)(src + i + 4);
    f16x8 o = { (f16)v0.x,(f16)v0.y,(f16)v0.z,(f16)v0.w,
                (f16)v1.x,(f16)v1.y,(f16)v1.z,(f16)v1.w };
    *(f16x8*)(dst + i) = o;
}

// ===========================================================================
// Blended expert layer, "big-K" formulation:
//   out[b,o] = act( sum_e (bc[b,e]*A[b,:]) . Wf[e,o,:] + sum_e bc[b,e]*bias[e,o] )
//
// v3 structure: 128x128 tile, 512 threads (8 waves), DOUBLE-BUFFERED LDS,
// one barrier per 32-K window (as v2), but TALL WAVES: each wave owns a
// 128m x 16n stripe (wave w -> cols w*16..w*16+15).
//   LDS frag traffic/window/wave: 8 B-frags (1/expert) + 8 A-frags = 16 KB
//   vs v2's 32 B + 2 A = 34 KB. Per-CU: 272 KB -> 128 KB/window, putting
//   LDS (~1540 cyc) under the MFMA pipe (~2483 cyc). B frags pay the x8
//   expert factor, A frags are hoisted + bc-scaled in registers -> tall
//   waves minimize (n_w/16)*8 + m_w/16.
// ===========================================================================
template<int KE, int N, int ACT, int SRC, typename OT>
__global__ __launch_bounds__(512, 2)
void blended_big(const f16* __restrict__ A, int ldA,
                 const float* __restrict__ x, const float* __restrict__ z,
                 const f16* __restrict__ Wf, const float* __restrict__ bias,
                 const float* __restrict__ bc, OT* __restrict__ out, int ldOut)
{
    constexpr int NCT = N / 128;
    constexpr int NW  = KE / 32;
    __shared__ __align__(16) f16 b_sh[2][NEXP * 128 * 32];   // 128 KB, glds dest
    __shared__ __align__(16) f16 a_sh[2][128][40];           // 20 KB, pad 40
    __shared__ float bc_sh[128][8];
    __shared__ float bias_sh[8][128];

    const int tid  = threadIdx.x;
    const int bid  = blockIdx.x;
    const int row0 = (bid / NCT) * 128;
    const int col0 = (bid % NCT) * 128;  // % NCT aligns col-slice with XCD L2
    const int wave = tid >> 6;
    const int lane = tid & 63;
    const int ln   = lane & 15;
    const int quad = lane >> 4;

    // one-time staging of bc and bias tiles
    for (int i = tid; i < 128 * 8; i += 512)
        bc_sh[i >> 3][i & 7] = bc[(size_t)(row0 + (i >> 3)) * NEXP + (i & 7)];
    for (int i = tid; i < 8 * 128; i += 512)
        bias_sh[i >> 7][i & 127] = bias[(size_t)(i >> 7) * N + col0 + (i & 127)];

    // A staging coords: thread -> (row 0..127, k-chunk 0..3)
    const int ar = tid >> 2;
    const int ac = tid & 3;
    // B staging lane constants (XOR-swizzled k-chunks):
    // chunk j*64+lane -> p=j*16+(lane>>2), stored kc = (lane&3)^((lane>>3)&3)
    const int kcl  = (lane & 3) ^ ((lane >> 3) & 3);
    const int prow = lane >> 2;           // 0..15
    // per-wave: stage expert e = wave (8 waves <-> 8 experts)
    const f16* wb = Wf + ((size_t)wave * N + col0 + prow) * KE + kcl * 8;
    // B frag-read lane constant: stored chunk for global chunk q=quad of row n
    const int csel = quad ^ ((ln >> 1) & 3);

    f32x4 acc[8] = {};

    float4 sv0, sv1;   // SRC==0 in-flight A staging regs
    f16x8  sa;         // SRC==1 in-flight A staging regs

    auto stage_issue = [&](int buf, int k0) {
        // A global loads FIRST (their waitcnt then leaves B glds in flight)
        if (SRC == 0) {
            int k = k0 + ac * 8;   // 800 % 8 == 0: chunk is pure-x or pure-z
            const float* s = (k < XDIM)
                ? x + (size_t)(row0 + ar) * XDIM + k
                : z + (size_t)(row0 + ar) * ZDIM + (k - XDIM);
            sv0 = *(const float4*)s;
            sv1 = *(const float4*)(s + 4);
        } else {
            sa = *(const f16x8*)(A + (size_t)(row0 + ar) * ldA + k0 + ac * 8);
        }
        // B tile: expert 'wave', 128x32 f16 via 8 glds16/thread (async)
        #pragma unroll
        for (int j = 0; j < 8; ++j)
            glds16(wb + k0 + (size_t)j * 16 * KE,
                   &b_sh[buf][(wave * 128 + j * 16) * 32]);
    };
    auto stage_commit = [&](int buf) {
        f16x8 av;
        if (SRC == 0) {
            av = (f16x8){ (f16)sv0.x,(f16)sv0.y,(f16)sv0.z,(f16)sv0.w,
                          (f16)sv1.x,(f16)sv1.y,(f16)sv1.z,(f16)sv1.w };
        } else {
            av = sa;
        }
        *(f16x8*)&a_sh[buf][ar][ac * 8] = av;
    };

    // prologue: fill buffer 0
    stage_issue(0, 0);
    stage_commit(0);
    __syncthreads();   // also covers bc_sh/bias_sh

    // per-lane f16 bc scale factors for A-frag rows (m = mi*16 + ln),
    // read from LDS after the prologue barrier (statically indexed -> VGPRs)
    f16 bcf[8][8];
    #pragma unroll
    for (int mi = 0; mi < 8; ++mi)
        #pragma unroll
        for (int e = 0; e < NEXP; ++e)
            bcf[mi][e] = (f16)bc_sh[mi * 16 + ln][e];

    int cur = 0;
    for (int t = 0; t < NW; ++t) {
        const bool pf = (t + 1 < NW);
        if (pf) stage_issue(cur ^ 1, (t + 1) * 32);   // prefetch next window

        // A frags: full 128-row column slice, reused across all 8 experts
        f16x8 af[8];
        #pragma unroll
        for (int mi = 0; mi < 8; ++mi)
            af[mi] = *(const f16x8*)&a_sh[cur][mi * 16 + ln][quad * 8];

        __builtin_amdgcn_s_setprio(1);
        #pragma unroll
        for (int e = 0; e < NEXP; ++e) {
            // single B frag per expert: rows n = wave*16 + ln, full K=32
            f16x8 bf = *(const f16x8*)
                &b_sh[cur][e * 4096 + (wave * 16 + ln) * 32 + csel * 8];
            #pragma unroll
            for (int mi = 0; mi < 8; ++mi) {
                f16x8 as = vscale(af[mi], bcf[mi][e]);
                acc[mi] = __builtin_amdgcn_mfma_f32_16x16x32_f16(
                    as, bf, acc[mi], 0, 0, 0);
            }
        }
        __builtin_amdgcn_s_setprio(0);

        if (pf) stage_commit(cur ^ 1);   // A write after compute
        __syncthreads();                 // single barrier per window (dbuf)
        cur ^= 1;
    }

    // epilogue: + sum_e bc*bias, activation, store
    const int cl = wave * 16 + ln;
    #pragma unroll
    for (int mi = 0; mi < 8; ++mi) {
        #pragma unroll
        for (int r = 0; r < 4; ++r) {
            int rl = mi * 16 + quad * 4 + r;
            size_t grow = (size_t)(row0 + rl) * ldOut;
            float v = acc[mi][r];
            #pragma unroll
            for (int e2 = 0; e2 < NEXP; ++e2)
                v += bc_sh[rl][e2] * bias_sh[e2][cl];
            if (ACT) v = elu_act(v);
            out[grow + col0 + cl] = (OT)v;
        }
    }
}

// ===========================================================================
extern "C" void kernel_launch(void* const* d_in, const int* in_sizes, int n_in,
                              void* d_out, int out_size, void* d_ws, size_t ws_size,
                              hipStream_t stream)
{
    const float* x   = (const float*)d_in[0];
    const float* z   = (const float*)d_in[1];
    const float* Wg1 = (const float*)d_in[2];
    const float* bg1 = (const float*)d_in[3];
    const float* Wg2 = (const float*)d_in[4];
    const float* bg2 = (const float*)d_in[5];
    const float* Wg3 = (const float*)d_in[6];
    const float* bg3 = (const float*)d_in[7];
    const float* W0  = (const float*)d_in[8];
    const float* b0  = (const float*)d_in[9];
    const float* W1  = (const float*)d_in[10];
    const float* b1  = (const float*)d_in[11];
    const float* W2  = (const float*)d_in[12];
    const float* b2  = (const float*)d_in[13];
    const float* W3  = (const float*)d_in[14];
    const float* b3  = (const float*)d_in[15];
    float* out = (float*)d_out;

    // workspace (~40 MB): wbuf f16 [8*1024*1088], hz_a/hz_b f16 [4096][1088],
    // g1/g2 f32 [4096][128], bc f32 [4096][8]
    char* ws = (char*)d_ws;
    f16*   wbuf = (f16*)ws;                 ws += (size_t)NEXP * HDIM * (HDIM + ZDIM) * 2;
    f16*   hz_a = (f16*)ws;                 ws += (size_t)BDIM * (HDIM + ZDIM) * 2;
    f16*   hz_b = (f16*)ws;                 ws += (size_t)BDIM * (HDIM + ZDIM) * 2;
    float* g1   = (float*)ws;               ws += (size_t)BDIM * GH * 4;
    float* g2   = (float*)ws;               ws += (size_t)BDIM * GH * 4;
    float* bcw  = (float*)ws;

    dim3 blk(256);
    dim3 blk512(512);

    // z-columns of hz buffers
    fill_z<<<dim3(BDIM * ZDIM / 4 / 256), blk, 0, stream>>>(z, hz_a, hz_b);

    // gating MLP (fp32)
    gemm_cat<1><<<dim3(BDIM/BMg, GH/BNg), blk, 0, stream>>>(x, XDIM, z, ZDIM, Wg1, bg1, g1, GH);
    gemm_cat<1><<<dim3(BDIM/BMg, GH/BNg), blk, 0, stream>>>(g1, GH, nullptr, 0, Wg2, bg2, g2, GH);
    gating3_softmax<<<dim3(BDIM/32), blk, 0, stream>>>(g2, Wg3, bg3, bcw);

    // blended expert layers: convert weights to f16, then big-K MFMA GEMM
    // grid = (4096/128) x (N/128) blocks of 512 threads
    w_to_f16<<<dim3(NEXP*HDIM*(XDIM+ZDIM)/8/256), blk, 0, stream>>>(W0, wbuf);
    blended_big<XDIM+ZDIM, HDIM, 1, 0, f16><<<dim3(32 * 8), blk512, 0, stream>>>(
        nullptr, 0, x, z, wbuf, b0, bcw, hz_a, HDIM + ZDIM);

    w_to_f16<<<dim3(NEXP*HDIM*(HDIM+ZDIM)/8/256), blk, 0, stream>>>(W1, wbuf);
    blended_big<HDIM+ZDIM, HDIM, 1, 1, f16><<<dim3(32 * 8), blk512, 0, stream>>>(
        hz_a, HDIM + ZDIM, nullptr, nullptr, wbuf, b1, bcw, hz_b, HDIM + ZDIM);

    w_to_f16<<<dim3(NEXP*HDIM*(HDIM+ZDIM)/8/256), blk, 0, stream>>>(W2, wbuf);
    blended_big<HDIM+ZDIM, HDIM, 1, 1, f16><<<dim3(32 * 8), blk512, 0, stream>>>(
        hz_b, HDIM + ZDIM, nullptr, nullptr, wbuf, b2, bcw, hz_a, HDIM + ZDIM);

    w_to_f16<<<dim3(NEXP*ODIM*HDIM/8/256), blk, 0, stream>>>(W3, wbuf);
    blended_big<HDIM, ODIM, 0, 1, float><<<dim3(32 * 6), blk512, 0, stream>>>(
        hz_a, HDIM + ZDIM, nullptr, nullptr, wbuf, b3, bcw, out, ODIM);
}

// Round 3
// 3867.102 us; speedup vs baseline: 1.4272x; 1.4272x over previous
//
#include <hip/hip_runtime.h>
#include <math.h>

// Problem constants
#define BDIM 4096
#define NEXP 8
#define HDIM 1024
#define XDIM 800
#define ZDIM 64
#define ODIM 768
#define GH   128

typedef _Float16 f16;
typedef f16   f16x8 __attribute__((ext_vector_type(8)));
typedef f16   f16x4 __attribute__((ext_vector_type(4)));
typedef float f32x4 __attribute__((ext_vector_type(4)));

__device__ __forceinline__ float elu_act(float x) {
    return x > 0.0f ? x : expm1f(x);
}

// async global->LDS, 16B per lane; LDS dest is wave-uniform base + lane*16
__device__ __forceinline__ void glds16(const void* g, void* l) {
    __builtin_amdgcn_global_load_lds(
        (const __attribute__((address_space(1))) void*)g,
        (__attribute__((address_space(3))) void*)l, 16, 0, 0);
}

__device__ __forceinline__ f16x8 vscale(f16x8 v, f16 s) {
    f16x8 r;
    #pragma unroll
    for (int i = 0; i < 8; ++i) r[i] = v[i] * s;
    return r;
}

// ===========================================================================
// fp32 tiled GEMM with implicit concat input (gating MLP only — small)
// ===========================================================================
#define BMg 64
#define BNg 64
#define BKg 32
#define PADg 68

template<int ACT>
__global__ __launch_bounds__(256)
void gemm_cat(const float* __restrict__ srcA, int KH,
              const float* __restrict__ srcZ, int KZ,
              const float* __restrict__ W, const float* __restrict__ bias,
              float* __restrict__ dst, int N)
{
    __shared__ float lds_a[BKg][PADg];
    __shared__ float lds_b[BKg][PADg];
    const int K = KH + KZ;
    const int row0 = blockIdx.x * BMg;
    const int col0 = blockIdx.y * BNg;
    const int tid = threadIdx.x;
    const int tx = tid & 15, ty = tid >> 4;

    float acc[4][4] = {};

    for (int k0 = 0; k0 < K; k0 += BKg) {
        #pragma unroll
        for (int it = 0; it < 2; ++it) {
            int idx = tid + it * 256;
            int r = idx >> 3;
            int f = idx & 7;
            int k = k0 + f * 4;
            const float* src; int col;
            if (k < KH) { src = srcA + (size_t)(row0 + r) * KH; col = k; }
            else        { src = srcZ + (size_t)(row0 + r) * KZ; col = k - KH; }
            float4 v = *(const float4*)(src + col);
            lds_a[f*4+0][r] = v.x; lds_a[f*4+1][r] = v.y;
            lds_a[f*4+2][r] = v.z; lds_a[f*4+3][r] = v.w;
        }
        #pragma unroll
        for (int it = 0; it < 2; ++it) {
            int idx = tid + it * 256;
            int c = idx >> 3;
            int f = idx & 7;
            int k = k0 + f * 4;
            float4 v = *(const float4*)(W + (size_t)(col0 + c) * K + k);
            lds_b[f*4+0][c] = v.x; lds_b[f*4+1][c] = v.y;
            lds_b[f*4+2][c] = v.z; lds_b[f*4+3][c] = v.w;
        }
        __syncthreads();
        #pragma unroll
        for (int j = 0; j < BKg; ++j) {
            float4 a4 = *(const float4*)&lds_a[j][ty*4];
            float4 b4 = *(const float4*)&lds_b[j][tx*4];
            float a[4] = {a4.x, a4.y, a4.z, a4.w};
            float b[4] = {b4.x, b4.y, b4.z, b4.w};
            #pragma unroll
            for (int i = 0; i < 4; ++i)
                #pragma unroll
                for (int jj = 0; jj < 4; ++jj)
                    acc[i][jj] += a[i] * b[jj];
        }
        __syncthreads();
    }

    #pragma unroll
    for (int i = 0; i < 4; ++i) {
        int r = row0 + ty*4 + i;
        float vals[4];
        #pragma unroll
        for (int j = 0; j < 4; ++j) {
            float v = acc[i][j] + bias[col0 + tx*4 + j];
            vals[j] = (ACT == 1) ? elu_act(v) : v;
        }
        *(float4*)(dst + (size_t)r * N + col0 + tx*4) =
            make_float4(vals[0], vals[1], vals[2], vals[3]);
    }
}

// ===========================================================================
// Gating layer 3 + softmax (fp32)
// ===========================================================================
__global__ __launch_bounds__(256)
void gating3_softmax(const float* __restrict__ g2, const float* __restrict__ Wg3,
                     const float* __restrict__ bg3, float* __restrict__ bc)
{
    __shared__ float w[NEXP * GH];
    __shared__ float bsh[NEXP];
    const int tid = threadIdx.x;
    for (int i = tid; i < NEXP * GH; i += 256) w[i] = Wg3[i];
    if (tid < NEXP) bsh[tid] = bg3[tid];
    __syncthreads();

    const int rowl = tid >> 3;
    const int o    = tid & 7;
    const int row  = blockIdx.x * 32 + rowl;
    const float* g = g2 + (size_t)row * GH;

    float s = bsh[o];
    for (int k = 0; k < GH; ++k) s += g[k] * w[o * GH + k];

    float m = s;
    #pragma unroll
    for (int d = 4; d >= 1; d >>= 1) m = fmaxf(m, __shfl_xor(m, d, 8));
    float e = expf(s - m);
    float sum = e;
    #pragma unroll
    for (int d = 4; d >= 1; d >>= 1) sum += __shfl_xor(sum, d, 8);

    bc[(size_t)blockIdx.x * 256 + tid] = e / sum;
}

// ===========================================================================
// Helper kernels
// ===========================================================================
// Fill z-columns (1024..1087) of both hz buffers with f16(z) (unscaled).
__global__ __launch_bounds__(256)
void fill_z(const float* __restrict__ z, f16* __restrict__ hz_a,
            f16* __restrict__ hz_b)
{
    int i = (blockIdx.x * 256 + threadIdx.x) * 4;      // over 4096*64
    int row = i >> 6;
    int col = i & 63;
    float4 v = *(const float4*)(z + i);
    f16x4 o = { (f16)v.x, (f16)v.y, (f16)v.z, (f16)v.w };
    size_t off = (size_t)row * (HDIM + ZDIM) + HDIM + col;
    *(f16x4*)(hz_a + off) = o;
    *(f16x4*)(hz_b + off) = o;
}

// fp32 -> f16 weight conversion, 8 elements/thread
__global__ __launch_bounds__(256)
void w_to_f16(const float* __restrict__ src, f16* __restrict__ dst)
{
    size_t i = ((size_t)blockIdx.x * 256 + threadIdx.x) * 8;
    float4 v0 = *(const float4*)(src + i);
    float4 v1 = *(const float4*)(src + i + 4);
    f16x8 o = { (f16)v0.x,(f16)v0.y,(f16)v0.z,(f16)v0.w,
                (f16)v1.x,(f16)v1.y,(f16)v1.z,(f16)v1.w };
    *(f16x8*)(dst + i) = o;
}

// ===========================================================================
// Blended expert layer, "big-K" formulation:
//   out[b,o] = act( sum_e (bc[b,e]*A[b,:]) . Wf[e,o,:] + sum_e bc[b,e]*bias[e,o] )
//
// v4 = v3 (tall waves: each wave owns 128m x 16n stripe; 8 B-frags + 8
// A-frags = 16 KB LDS frag traffic per wave per window, vs v2's 34 KB)
// with the v3 REGISTER SPILL fixed:
//   - __launch_bounds__(512, 1): v3's (512,2) was interpreted as 2 blocks/CU
//     -> 128-VGPR cap -> ~30 spilled regs -> 3.8 GB/dispatch scratch traffic
//     (FETCH_SIZE 44MB->3.8GB, MfmaUtil 1.8%). LDS already caps us at
//     1 block/CU, so the laxer bound costs nothing.
//   - bc scales packed as f16x8 bcfv[8] (32 VGPRs, statically indexed)
//     instead of 64 unpacked _Float16 scalars (64 VGPRs).
// Live set: acc 32 + af 32 + bcfv 32 + ~35 misc ~= 140 VGPRs, no spill.
// ===========================================================================
template<int KE, int N, int ACT, int SRC, typename OT>
__global__ __launch_bounds__(512, 1)
void blended_big(const f16* __restrict__ A, int ldA,
                 const float* __restrict__ x, const float* __restrict__ z,
                 const f16* __restrict__ Wf, const float* __restrict__ bias,
                 const float* __restrict__ bc, OT* __restrict__ out, int ldOut)
{
    constexpr int NCT = N / 128;
    constexpr int NW  = KE / 32;
    __shared__ __align__(16) f16 b_sh[2][NEXP * 128 * 32];   // 128 KB, glds dest
    __shared__ __align__(16) f16 a_sh[2][128][40];           // 20 KB, pad 40
    __shared__ float bc_sh[128][8];
    __shared__ float bias_sh[8][128];

    const int tid  = threadIdx.x;
    const int bid  = blockIdx.x;
    const int row0 = (bid / NCT) * 128;
    const int col0 = (bid % NCT) * 128;  // % NCT aligns col-slice with XCD L2
    const int wave = tid >> 6;
    const int lane = tid & 63;
    const int ln   = lane & 15;
    const int quad = lane >> 4;

    // one-time staging of bc and bias tiles (for the epilogue)
    for (int i = tid; i < 128 * 8; i += 512)
        bc_sh[i >> 3][i & 7] = bc[(size_t)(row0 + (i >> 3)) * NEXP + (i & 7)];
    for (int i = tid; i < 8 * 128; i += 512)
        bias_sh[i >> 7][i & 127] = bias[(size_t)(i >> 7) * N + col0 + (i & 127)];

    // per-lane bc scale factors for A-frag rows (m = mi*16 + ln), PACKED:
    // bcfv[mi][e] = bc[row0 + mi*16 + ln][e] as f16. 8x f16x8 = 32 VGPRs.
    f16x8 bcfv[8];
    #pragma unroll
    for (int mi = 0; mi < 8; ++mi) {
        const float* bp = bc + (size_t)(row0 + mi * 16 + ln) * NEXP;
        float4 c0 = *(const float4*)bp;
        float4 c1 = *(const float4*)(bp + 4);
        bcfv[mi] = (f16x8){ (f16)c0.x,(f16)c0.y,(f16)c0.z,(f16)c0.w,
                            (f16)c1.x,(f16)c1.y,(f16)c1.z,(f16)c1.w };
    }

    // A staging coords: thread -> (row 0..127, k-chunk 0..3)
    const int ar = tid >> 2;
    const int ac = tid & 3;
    // B staging lane constants (XOR-swizzled k-chunks):
    // chunk j*64+lane -> p=j*16+(lane>>2), stored kc = (lane&3)^((lane>>3)&3)
    const int kcl  = (lane & 3) ^ ((lane >> 3) & 3);
    const int prow = lane >> 2;           // 0..15
    // per-wave: stage expert e = wave (8 waves <-> 8 experts)
    const f16* wb = Wf + ((size_t)wave * N + col0 + prow) * KE + kcl * 8;
    // B frag-read lane constant: stored chunk for global chunk q=quad of row n
    const int csel = quad ^ ((ln >> 1) & 3);

    f32x4 acc[8] = {};

    float4 sv0, sv1;   // SRC==0 in-flight A staging regs
    f16x8  sa;         // SRC==1 in-flight A staging regs

    auto stage_issue = [&](int buf, int k0) {
        // A global loads FIRST (their waitcnt then leaves B glds in flight)
        if (SRC == 0) {
            int k = k0 + ac * 8;   // 800 % 8 == 0: chunk is pure-x or pure-z
            const float* s = (k < XDIM)
                ? x + (size_t)(row0 + ar) * XDIM + k
                : z + (size_t)(row0 + ar) * ZDIM + (k - XDIM);
            sv0 = *(const float4*)s;
            sv1 = *(const float4*)(s + 4);
        } else {
            sa = *(const f16x8*)(A + (size_t)(row0 + ar) * ldA + k0 + ac * 8);
        }
        // B tile: expert 'wave', 128x32 f16 via 8 glds16/thread (async)
        #pragma unroll
        for (int j = 0; j < 8; ++j)
            glds16(wb + k0 + (size_t)j * 16 * KE,
                   &b_sh[buf][(wave * 128 + j * 16) * 32]);
    };
    auto stage_commit = [&](int buf) {
        f16x8 av;
        if (SRC == 0) {
            av = (f16x8){ (f16)sv0.x,(f16)sv0.y,(f16)sv0.z,(f16)sv0.w,
                          (f16)sv1.x,(f16)sv1.y,(f16)sv1.z,(f16)sv1.w };
        } else {
            av = sa;
        }
        *(f16x8*)&a_sh[buf][ar][ac * 8] = av;
    };

    // prologue: fill buffer 0
    stage_issue(0, 0);
    stage_commit(0);
    __syncthreads();   // also covers bc_sh/bias_sh

    int cur = 0;
    for (int t = 0; t < NW; ++t) {
        const bool pf = (t + 1 < NW);
        if (pf) stage_issue(cur ^ 1, (t + 1) * 32);   // prefetch next window

        // A frags: full 128-row column slice, reused across all 8 experts
        f16x8 af[8];
        #pragma unroll
        for (int mi = 0; mi < 8; ++mi)
            af[mi] = *(const f16x8*)&a_sh[cur][mi * 16 + ln][quad * 8];

        __builtin_amdgcn_s_setprio(1);
        #pragma unroll
        for (int e = 0; e < NEXP; ++e) {
            // single B frag per expert: rows n = wave*16 + ln, full K=32
            f16x8 bf = *(const f16x8*)
                &b_sh[cur][e * 4096 + (wave * 16 + ln) * 32 + csel * 8];
            #pragma unroll
            for (int mi = 0; mi < 8; ++mi) {
                f16x8 as = vscale(af[mi], bcfv[mi][e]);
                acc[mi] = __builtin_amdgcn_mfma_f32_16x16x32_f16(
                    as, bf, acc[mi], 0, 0, 0);
            }
        }
        __builtin_amdgcn_s_setprio(0);

        if (pf) stage_commit(cur ^ 1);   // A write after compute
        __syncthreads();                 // single barrier per window (dbuf)
        cur ^= 1;
    }

    // epilogue: + sum_e bc*bias, activation, store
    const int cl = wave * 16 + ln;
    #pragma unroll
    for (int mi = 0; mi < 8; ++mi) {
        #pragma unroll
        for (int r = 0; r < 4; ++r) {
            int rl = mi * 16 + quad * 4 + r;
            size_t grow = (size_t)(row0 + rl) * ldOut;
            float v = acc[mi][r];
            #pragma unroll
            for (int e2 = 0; e2 < NEXP; ++e2)
                v += bc_sh[rl][e2] * bias_sh[e2][cl];
            if (ACT) v = elu_act(v);
            out[grow + col0 + cl] = (OT)v;
        }
    }
}

// ===========================================================================
extern "C" void kernel_launch(void* const* d_in, const int* in_sizes, int n_in,
                              void* d_out, int out_size, void* d_ws, size_t ws_size,
                              hipStream_t stream)
{
    const float* x   = (const float*)d_in[0];
    const float* z   = (const float*)d_in[1];
    const float* Wg1 = (const float*)d_in[2];
    const float* bg1 = (const float*)d_in[3];
    const float* Wg2 = (const float*)d_in[4];
    const float* bg2 = (const float*)d_in[5];
    const float* Wg3 = (const float*)d_in[6];
    const float* bg3 = (const float*)d_in[7];
    const float* W0  = (const float*)d_in[8];
    const float* b0  = (const float*)d_in[9];
    const float* W1  = (const float*)d_in[10];
    const float* b1  = (const float*)d_in[11];
    const float* W2  = (const float*)d_in[12];
    const float* b2  = (const float*)d_in[13];
    const float* W3  = (const float*)d_in[14];
    const float* b3  = (const float*)d_in[15];
    float* out = (float*)d_out;

    // workspace (~40 MB): wbuf f16 [8*1024*1088], hz_a/hz_b f16 [4096][1088],
    // g1/g2 f32 [4096][128], bc f32 [4096][8]
    char* ws = (char*)d_ws;
    f16*   wbuf = (f16*)ws;                 ws += (size_t)NEXP * HDIM * (HDIM + ZDIM) * 2;
    f16*   hz_a = (f16*)ws;                 ws += (size_t)BDIM * (HDIM + ZDIM) * 2;
    f16*   hz_b = (f16*)ws;                 ws += (size_t)BDIM * (HDIM + ZDIM) * 2;
    float* g1   = (float*)ws;               ws += (size_t)BDIM * GH * 4;
    float* g2   = (float*)ws;               ws += (size_t)BDIM * GH * 4;
    float* bcw  = (float*)ws;

    dim3 blk(256);
    dim3 blk512(512);

    // z-columns of hz buffers
    fill_z<<<dim3(BDIM * ZDIM / 4 / 256), blk, 0, stream>>>(z, hz_a, hz_b);

    // gating MLP (fp32)
    gemm_cat<1><<<dim3(BDIM/BMg, GH/BNg), blk, 0, stream>>>(x, XDIM, z, ZDIM, Wg1, bg1, g1, GH);
    gemm_cat<1><<<dim3(BDIM/BMg, GH/BNg), blk, 0, stream>>>(g1, GH, nullptr, 0, Wg2, bg2, g2, GH);
    gating3_softmax<<<dim3(BDIM/32), blk, 0, stream>>>(g2, Wg3, bg3, bcw);

    // blended expert layers: convert weights to f16, then big-K MFMA GEMM
    // grid = (4096/128) x (N/128) blocks of 512 threads
    w_to_f16<<<dim3(NEXP*HDIM*(XDIM+ZDIM)/8/256), blk, 0, stream>>>(W0, wbuf);
    blended_big<XDIM+ZDIM, HDIM, 1, 0, f16><<<dim3(32 * 8), blk512, 0, stream>>>(
        nullptr, 0, x, z, wbuf, b0, bcw, hz_a, HDIM + ZDIM);

    w_to_f16<<<dim3(NEXP*HDIM*(HDIM+ZDIM)/8/256), blk, 0, stream>>>(W1, wbuf);
    blended_big<HDIM+ZDIM, HDIM, 1, 1, f16><<<dim3(32 * 8), blk512, 0, stream>>>(
        hz_a, HDIM + ZDIM, nullptr, nullptr, wbuf, b1, bcw, hz_b, HDIM + ZDIM);

    w_to_f16<<<dim3(NEXP*HDIM*(HDIM+ZDIM)/8/256), blk, 0, stream>>>(W2, wbuf);
    blended_big<HDIM+ZDIM, HDIM, 1, 1, f16><<<dim3(32 * 8), blk512, 0, stream>>>(
        hz_b, HDIM + ZDIM, nullptr, nullptr, wbuf, b2, bcw, hz_a, HDIM + ZDIM);

    w_to_f16<<<dim3(NEXP*ODIM*HDIM/8/256), blk, 0, stream>>>(W3, wbuf);
    blended_big<HDIM, ODIM, 0, 1, float><<<dim3(32 * 6), blk512, 0, stream>>>(
        hz_a, HDIM + ZDIM, nullptr, nullptr, wbuf, b3, bcw, out, ODIM);
}

// Round 4
// 615.468 us; speedup vs baseline: 8.9676x; 6.2832x over previous
//
#include <hip/hip_runtime.h>
#include <math.h>

// Problem constants
#define BDIM 4096
#define NEXP 8
#define HDIM 1024
#define XDIM 800
#define ZDIM 64
#define ODIM 768
#define GH   128

typedef _Float16 f16;
typedef f16   f16x8 __attribute__((ext_vector_type(8)));
typedef f16   f16x4 __attribute__((ext_vector_type(4)));
typedef float f32x4 __attribute__((ext_vector_type(4)));

__device__ __forceinline__ float elu_act(float x) {
    return x > 0.0f ? x : expm1f(x);
}

// async global->LDS, 16B per lane; LDS dest is wave-uniform base + lane*16
__device__ __forceinline__ void glds16(const void* g, void* l) {
    __builtin_amdgcn_global_load_lds(
        (const __attribute__((address_space(1))) void*)g,
        (__attribute__((address_space(3))) void*)l, 16, 0, 0);
}

__device__ __forceinline__ f16x8 vscale(f16x8 v, f16 s) {
    f16x8 r;
    #pragma unroll
    for (int i = 0; i < 8; ++i) r[i] = v[i] * s;
    return r;
}

// ===========================================================================
// fp32 tiled GEMM with implicit concat input (gating MLP only — small)
// ===========================================================================
#define BMg 64
#define BNg 64
#define BKg 32
#define PADg 68

template<int ACT>
__global__ __launch_bounds__(256)
void gemm_cat(const float* __restrict__ srcA, int KH,
              const float* __restrict__ srcZ, int KZ,
              const float* __restrict__ W, const float* __restrict__ bias,
              float* __restrict__ dst, int N)
{
    __shared__ float lds_a[BKg][PADg];
    __shared__ float lds_b[BKg][PADg];
    const int K = KH + KZ;
    const int row0 = blockIdx.x * BMg;
    const int col0 = blockIdx.y * BNg;
    const int tid = threadIdx.x;
    const int tx = tid & 15, ty = tid >> 4;

    float acc[4][4] = {};

    for (int k0 = 0; k0 < K; k0 += BKg) {
        #pragma unroll
        for (int it = 0; it < 2; ++it) {
            int idx = tid + it * 256;
            int r = idx >> 3;
            int f = idx & 7;
            int k = k0 + f * 4;
            const float* src; int col;
            if (k < KH) { src = srcA + (size_t)(row0 + r) * KH; col = k; }
            else        { src = srcZ + (size_t)(row0 + r) * KZ; col = k - KH; }
            float4 v = *(const float4*)(src + col);
            lds_a[f*4+0][r] = v.x; lds_a[f*4+1][r] = v.y;
            lds_a[f*4+2][r] = v.z; lds_a[f*4+3][r] = v.w;
        }
        #pragma unroll
        for (int it = 0; it < 2; ++it) {
            int idx = tid + it * 256;
            int c = idx >> 3;
            int f = idx & 7;
            int k = k0 + f * 4;
            float4 v = *(const float4*)(W + (size_t)(col0 + c) * K + k);
            lds_b[f*4+0][c] = v.x; lds_b[f*4+1][c] = v.y;
            lds_b[f*4+2][c] = v.z; lds_b[f*4+3][c] = v.w;
        }
        __syncthreads();
        #pragma unroll
        for (int j = 0; j < BKg; ++j) {
            float4 a4 = *(const float4*)&lds_a[j][ty*4];
            float4 b4 = *(const float4*)&lds_b[j][tx*4];
            float a[4] = {a4.x, a4.y, a4.z, a4.w};
            float b[4] = {b4.x, b4.y, b4.z, b4.w};
            #pragma unroll
            for (int i = 0; i < 4; ++i)
                #pragma unroll
                for (int jj = 0; jj < 4; ++jj)
                    acc[i][jj] += a[i] * b[jj];
        }
        __syncthreads();
    }

    #pragma unroll
    for (int i = 0; i < 4; ++i) {
        int r = row0 + ty*4 + i;
        float vals[4];
        #pragma unroll
        for (int j = 0; j < 4; ++j) {
            float v = acc[i][j] + bias[col0 + tx*4 + j];
            vals[j] = (ACT == 1) ? elu_act(v) : v;
        }
        *(float4*)(dst + (size_t)r * N + col0 + tx*4) =
            make_float4(vals[0], vals[1], vals[2], vals[3]);
    }
}

// ===========================================================================
// Gating layer 3 + softmax (fp32)
// ===========================================================================
__global__ __launch_bounds__(256)
void gating3_softmax(const float* __restrict__ g2, const float* __restrict__ Wg3,
                     const float* __restrict__ bg3, float* __restrict__ bc)
{
    __shared__ float w[NEXP * GH];
    __shared__ float bsh[NEXP];
    const int tid = threadIdx.x;
    for (int i = tid; i < NEXP * GH; i += 256) w[i] = Wg3[i];
    if (tid < NEXP) bsh[tid] = bg3[tid];
    __syncthreads();

    const int rowl = tid >> 3;
    const int o    = tid & 7;
    const int row  = blockIdx.x * 32 + rowl;
    const float* g = g2 + (size_t)row * GH;

    float s = bsh[o];
    for (int k = 0; k < GH; ++k) s += g[k] * w[o * GH + k];

    float m = s;
    #pragma unroll
    for (int d = 4; d >= 1; d >>= 1) m = fmaxf(m, __shfl_xor(m, d, 8));
    float e = expf(s - m);
    float sum = e;
    #pragma unroll
    for (int d = 4; d >= 1; d >>= 1) sum += __shfl_xor(sum, d, 8);

    bc[(size_t)blockIdx.x * 256 + tid] = e / sum;
}

// ===========================================================================
// Helper kernels
// ===========================================================================
// Fill z-columns (1024..1087) of both hz buffers with f16(z) (unscaled).
__global__ __launch_bounds__(256)
void fill_z(const float* __restrict__ z, f16* __restrict__ hz_a,
            f16* __restrict__ hz_b)
{
    int i = (blockIdx.x * 256 + threadIdx.x) * 4;      // over 4096*64
    int row = i >> 6;
    int col = i & 63;
    float4 v = *(const float4*)(z + i);
    f16x4 o = { (f16)v.x, (f16)v.y, (f16)v.z, (f16)v.w };
    size_t off = (size_t)row * (HDIM + ZDIM) + HDIM + col;
    *(f16x4*)(hz_a + off) = o;
    *(f16x4*)(hz_b + off) = o;
}

// fp32 -> f16 weight conversion, 8 elements/thread
__global__ __launch_bounds__(256)
void w_to_f16(const float* __restrict__ src, f16* __restrict__ dst)
{
    size_t i = ((size_t)blockIdx.x * 256 + threadIdx.x) * 8;
    float4 v0 = *(const float4*)(src + i);
    float4 v1 = *(const float4*)(src + i + 4);
    f16x8 o = { (f16)v0.x,(f16)v0.y,(f16)v0.z,(f16)v0.w,
                (f16)v1.x,(f16)v1.y,(f16)v1.z,(f16)v1.w };
    *(f16x8*)(dst + i) = o;
}

// ===========================================================================
// Blended expert layer, "big-K" formulation:
//   out[b,o] = act( sum_e (bc[b,e]*A[b,:]) . Wf[e,o,:] + sum_e bc[b,e]*bias[e,o] )
//
// v5: wave shape 64m x 32n (2 b-halves x 4 col-groups of the 128x128 tile).
// Register/LDS sweet spot:
//   frags/wave/window = 2(n-tiles)x8(experts) B + 4 A = 20 KB
//     (v2: 34 KB -> LDS-bound at 272 KB/CU; v3/v4: 16 KB but 130+ regs -> spill)
//   live regs ~ acc 32 + af 16 + bcfv 16 + bf 8 + misc ~30 = ~105 < 128 budget.
// v3/v4 post-mortem: VGPR budget pinned at 128 regardless of __launch_bounds__
// 2nd arg; bcfv (32 dw) spilled & reloaded per expert -> 3.1 GB/dispatch
// scratch reads. v5 fits under 128; amdgpu_waves_per_eu(2) additionally
// grants a 256 cap (occupancy is LDS-capped at 2 waves/EU anyway).
// ===========================================================================
template<int KE, int N, int ACT, int SRC, typename OT>
__global__ __launch_bounds__(512)
__attribute__((amdgpu_waves_per_eu(2)))
void blended_big(const f16* __restrict__ A, int ldA,
                 const float* __restrict__ x, const float* __restrict__ z,
                 const f16* __restrict__ Wf, const float* __restrict__ bias,
                 const float* __restrict__ bc, OT* __restrict__ out, int ldOut)
{
    constexpr int NCT = N / 128;
    constexpr int NW  = KE / 32;
    __shared__ __align__(16) f16 b_sh[2][NEXP * 128 * 32];   // 128 KB, glds dest
    __shared__ __align__(16) f16 a_sh[2][128][40];           // 20 KB, pad 40
    __shared__ float bc_sh[128][8];
    __shared__ float bias_sh[8][128];

    const int tid  = threadIdx.x;
    const int bid  = blockIdx.x;
    const int row0 = (bid / NCT) * 128;
    const int col0 = (bid % NCT) * 128;  // % NCT aligns col-slice with XCD L2
    const int wave = tid >> 6;
    const int lane = tid & 63;
    const int ln   = lane & 15;
    const int quad = lane >> 4;
    const int bhalf = wave >> 2;          // 0..1 : rows [bhalf*64, +64)
    const int ocol  = wave & 3;           // 0..3 : cols [ocol*32, +32)

    // one-time staging of bc and bias tiles (for the epilogue)
    for (int i = tid; i < 128 * 8; i += 512)
        bc_sh[i >> 3][i & 7] = bc[(size_t)(row0 + (i >> 3)) * NEXP + (i & 7)];
    for (int i = tid; i < 8 * 128; i += 512)
        bias_sh[i >> 7][i & 127] = bias[(size_t)(i >> 7) * N + col0 + (i & 127)];

    // per-lane bc scale factors for A-frag rows (m = bhalf*64 + mi*16 + ln),
    // PACKED: bcfv[mi][e]. 4x f16x8 = 16 VGPRs.
    f16x8 bcfv[4];
    #pragma unroll
    for (int mi = 0; mi < 4; ++mi) {
        const float* bp = bc + (size_t)(row0 + bhalf*64 + mi*16 + ln) * NEXP;
        float4 c0 = *(const float4*)bp;
        float4 c1 = *(const float4*)(bp + 4);
        bcfv[mi] = (f16x8){ (f16)c0.x,(f16)c0.y,(f16)c0.z,(f16)c0.w,
                            (f16)c1.x,(f16)c1.y,(f16)c1.z,(f16)c1.w };
    }

    // A staging coords: thread -> (row 0..127, k-chunk 0..3)
    const int ar = tid >> 2;
    const int ac = tid & 3;
    // B staging lane constants (XOR-swizzled k-chunks):
    // chunk j*64+lane -> p=j*16+(lane>>2), stored kc = (lane&3)^((lane>>3)&3)
    const int kcl  = (lane & 3) ^ ((lane >> 3) & 3);
    const int prow = lane >> 2;           // 0..15
    // per-wave: stage expert e = wave (8 waves <-> 8 experts)
    const f16* wb = Wf + ((size_t)wave * N + col0 + prow) * KE + kcl * 8;
    // B frag-read lane constant: stored chunk for global chunk q=quad of row n
    const int csel = quad ^ ((ln >> 1) & 3);

    f32x4 acc[4][2] = {};

    float4 sv0, sv1;   // SRC==0 in-flight A staging regs
    f16x8  sa;         // SRC==1 in-flight A staging regs

    auto stage_issue = [&](int buf, int k0) {
        // A global loads FIRST (their waitcnt then leaves B glds in flight)
        if (SRC == 0) {
            int k = k0 + ac * 8;   // 800 % 8 == 0: chunk is pure-x or pure-z
            const float* s = (k < XDIM)
                ? x + (size_t)(row0 + ar) * XDIM + k
                : z + (size_t)(row0 + ar) * ZDIM + (k - XDIM);
            sv0 = *(const float4*)s;
            sv1 = *(const float4*)(s + 4);
        } else {
            sa = *(const f16x8*)(A + (size_t)(row0 + ar) * ldA + k0 + ac * 8);
        }
        // B tile: expert 'wave', 128x32 f16 via 8 glds16/thread (async)
        #pragma unroll
        for (int j = 0; j < 8; ++j)
            glds16(wb + k0 + (size_t)j * 16 * KE,
                   &b_sh[buf][(wave * 128 + j * 16) * 32]);
    };
    auto stage_commit = [&](int buf) {
        f16x8 av;
        if (SRC == 0) {
            av = (f16x8){ (f16)sv0.x,(f16)sv0.y,(f16)sv0.z,(f16)sv0.w,
                          (f16)sv1.x,(f16)sv1.y,(f16)sv1.z,(f16)sv1.w };
        } else {
            av = sa;
        }
        *(f16x8*)&a_sh[buf][ar][ac * 8] = av;
    };

    // prologue: fill buffer 0
    stage_issue(0, 0);
    stage_commit(0);
    __syncthreads();   // also covers bc_sh/bias_sh

    int cur = 0;
    for (int t = 0; t < NW; ++t) {
        const bool pf = (t + 1 < NW);
        if (pf) stage_issue(cur ^ 1, (t + 1) * 32);   // prefetch next window

        // A frags: 64-row half, reused across all 8 experts (and 2 n-tiles)
        f16x8 af[4];
        #pragma unroll
        for (int mi = 0; mi < 4; ++mi)
            af[mi] = *(const f16x8*)&a_sh[cur][bhalf*64 + mi*16 + ln][quad * 8];

        __builtin_amdgcn_s_setprio(1);
        #pragma unroll
        for (int e = 0; e < NEXP; ++e) {
            // two B frags per expert: cols n = ocol*32 + {0,16} + ln
            f16x8 bf0 = *(const f16x8*)
                &b_sh[cur][e * 4096 + (ocol*32 +      ln) * 32 + csel * 8];
            f16x8 bf1 = *(const f16x8*)
                &b_sh[cur][e * 4096 + (ocol*32 + 16 + ln) * 32 + csel * 8];
            #pragma unroll
            for (int mi = 0; mi < 4; ++mi) {
                f16x8 as = vscale(af[mi], bcfv[mi][e]);
                acc[mi][0] = __builtin_amdgcn_mfma_f32_16x16x32_f16(
                    as, bf0, acc[mi][0], 0, 0, 0);
                acc[mi][1] = __builtin_amdgcn_mfma_f32_16x16x32_f16(
                    as, bf1, acc[mi][1], 0, 0, 0);
            }
        }
        __builtin_amdgcn_s_setprio(0);

        if (pf) stage_commit(cur ^ 1);   // A write after compute
        __syncthreads();                 // single barrier per window (dbuf)
        cur ^= 1;
    }

    // epilogue: + sum_e bc*bias, activation, store
    #pragma unroll
    for (int mi = 0; mi < 4; ++mi) {
        #pragma unroll
        for (int r = 0; r < 4; ++r) {
            int rl = bhalf*64 + mi*16 + quad*4 + r;
            size_t grow = (size_t)(row0 + rl) * ldOut;
            #pragma unroll
            for (int nj = 0; nj < 2; ++nj) {
                int cl = ocol*32 + nj*16 + ln;
                float v = acc[mi][nj][r];
                #pragma unroll
                for (int e2 = 0; e2 < NEXP; ++e2)
                    v += bc_sh[rl][e2] * bias_sh[e2][cl];
                if (ACT) v = elu_act(v);
                out[grow + col0 + cl] = (OT)v;
            }
        }
    }
}

// ===========================================================================
extern "C" void kernel_launch(void* const* d_in, const int* in_sizes, int n_in,
                              void* d_out, int out_size, void* d_ws, size_t ws_size,
                              hipStream_t stream)
{
    const float* x   = (const float*)d_in[0];
    const float* z   = (const float*)d_in[1];
    const float* Wg1 = (const float*)d_in[2];
    const float* bg1 = (const float*)d_in[3];
    const float* Wg2 = (const float*)d_in[4];
    const float* bg2 = (const float*)d_in[5];
    const float* Wg3 = (const float*)d_in[6];
    const float* bg3 = (const float*)d_in[7];
    const float* W0  = (const float*)d_in[8];
    const float* b0  = (const float*)d_in[9];
    const float* W1  = (const float*)d_in[10];
    const float* b1  = (const float*)d_in[11];
    const float* W2  = (const float*)d_in[12];
    const float* b2  = (const float*)d_in[13];
    const float* W3  = (const float*)d_in[14];
    const float* b3  = (const float*)d_in[15];
    float* out = (float*)d_out;

    // workspace (~40 MB): wbuf f16 [8*1024*1088], hz_a/hz_b f16 [4096][1088],
    // g1/g2 f32 [4096][128], bc f32 [4096][8]
    char* ws = (char*)d_ws;
    f16*   wbuf = (f16*)ws;                 ws += (size_t)NEXP * HDIM * (HDIM + ZDIM) * 2;
    f16*   hz_a = (f16*)ws;                 ws += (size_t)BDIM * (HDIM + ZDIM) * 2;
    f16*   hz_b = (f16*)ws;                 ws += (size_t)BDIM * (HDIM + ZDIM) * 2;
    float* g1   = (float*)ws;               ws += (size_t)BDIM * GH * 4;
    float* g2   = (float*)ws;               ws += (size_t)BDIM * GH * 4;
    float* bcw  = (float*)ws;

    dim3 blk(256);
    dim3 blk512(512);

    // z-columns of hz buffers
    fill_z<<<dim3(BDIM * ZDIM / 4 / 256), blk, 0, stream>>>(z, hz_a, hz_b);

    // gating MLP (fp32)
    gemm_cat<1><<<dim3(BDIM/BMg, GH/BNg), blk, 0, stream>>>(x, XDIM, z, ZDIM, Wg1, bg1, g1, GH);
    gemm_cat<1><<<dim3(BDIM/BMg, GH/BNg), blk, 0, stream>>>(g1, GH, nullptr, 0, Wg2, bg2, g2, GH);
    gating3_softmax<<<dim3(BDIM/32), blk, 0, stream>>>(g2, Wg3, bg3, bcw);

    // blended expert layers: convert weights to f16, then big-K MFMA GEMM
    // grid = (4096/128) x (N/128) blocks of 512 threads
    w_to_f16<<<dim3(NEXP*HDIM*(XDIM+ZDIM)/8/256), blk, 0, stream>>>(W0, wbuf);
    blended_big<XDIM+ZDIM, HDIM, 1, 0, f16><<<dim3(32 * 8), blk512, 0, stream>>>(
        nullptr, 0, x, z, wbuf, b0, bcw, hz_a, HDIM + ZDIM);

    w_to_f16<<<dim3(NEXP*HDIM*(HDIM+ZDIM)/8/256), blk, 0, stream>>>(W1, wbuf);
    blended_big<HDIM+ZDIM, HDIM, 1, 1, f16><<<dim3(32 * 8), blk512, 0, stream>>>(
        hz_a, HDIM + ZDIM, nullptr, nullptr, wbuf, b1, bcw, hz_b, HDIM + ZDIM);

    w_to_f16<<<dim3(NEXP*HDIM*(HDIM+ZDIM)/8/256), blk, 0, stream>>>(W2, wbuf);
    blended_big<HDIM+ZDIM, HDIM, 1, 1, f16><<<dim3(32 * 8), blk512, 0, stream>>>(
        hz_b, HDIM + ZDIM, nullptr, nullptr, wbuf, b2, bcw, hz_a, HDIM + ZDIM);

    w_to_f16<<<dim3(NEXP*ODIM*HDIM/8/256), blk, 0, stream>>>(W3, wbuf);
    blended_big<HDIM, ODIM, 0, 1, float><<<dim3(32 * 6), blk512, 0, stream>>>(
        hz_a, HDIM + ZDIM, nullptr, nullptr, wbuf, b3, bcw, out, ODIM);
}

// Round 7
// 611.099 us; speedup vs baseline: 9.0317x; 1.0072x over previous
//
#include <hip/hip_runtime.h>
#include <math.h>

// Problem constants
#define BDIM 4096
#define NEXP 8
#define HDIM 1024
#define XDIM 800
#define ZDIM 64
#define ODIM 768
#define GH   128

typedef _Float16 f16;
typedef f16   f16x8 __attribute__((ext_vector_type(8)));
typedef f16   f16x4 __attribute__((ext_vector_type(4)));
typedef float f32x4 __attribute__((ext_vector_type(4)));

__device__ __forceinline__ float elu_act(float x) {
    return x > 0.0f ? x : expm1f(x);
}

// async global->LDS, 16B per lane; LDS dest is wave-uniform base + lane*16
__device__ __forceinline__ void glds16(const void* g, void* l) {
    __builtin_amdgcn_global_load_lds(
        (const __attribute__((address_space(1))) void*)g,
        (__attribute__((address_space(3))) void*)l, 16, 0, 0);
}

__device__ __forceinline__ f16x8 vscale(f16x8 v, f16 s) {
    f16x8 r;
    #pragma unroll
    for (int i = 0; i < 8; ++i) r[i] = v[i] * s;
    return r;
}

// ===========================================================================
// fp32 tiled GEMM with implicit concat input (gating MLP only — small)
// ===========================================================================
#define BMg 64
#define BNg 64
#define BKg 32
#define PADg 68

template<int ACT>
__global__ __launch_bounds__(256)
void gemm_cat(const float* __restrict__ srcA, int KH,
              const float* __restrict__ srcZ, int KZ,
              const float* __restrict__ W, const float* __restrict__ bias,
              float* __restrict__ dst, int N)
{
    __shared__ float lds_a[BKg][PADg];
    __shared__ float lds_b[BKg][PADg];
    const int K = KH + KZ;
    const int row0 = blockIdx.x * BMg;
    const int col0 = blockIdx.y * BNg;
    const int tid = threadIdx.x;
    const int tx = tid & 15, ty = tid >> 4;

    float acc[4][4] = {};

    for (int k0 = 0; k0 < K; k0 += BKg) {
        #pragma unroll
        for (int it = 0; it < 2; ++it) {
            int idx = tid + it * 256;
            int r = idx >> 3;
            int f = idx & 7;
            int k = k0 + f * 4;
            const float* src; int col;
            if (k < KH) { src = srcA + (size_t)(row0 + r) * KH; col = k; }
            else        { src = srcZ + (size_t)(row0 + r) * KZ; col = k - KH; }
            float4 v = *(const float4*)(src + col);
            lds_a[f*4+0][r] = v.x; lds_a[f*4+1][r] = v.y;
            lds_a[f*4+2][r] = v.z; lds_a[f*4+3][r] = v.w;
        }
        #pragma unroll
        for (int it = 0; it < 2; ++it) {
            int idx = tid + it * 256;
            int c = idx >> 3;
            int f = idx & 7;
            int k = k0 + f * 4;
            float4 v = *(const float4*)(W + (size_t)(col0 + c) * K + k);
            lds_b[f*4+0][c] = v.x; lds_b[f*4+1][c] = v.y;
            lds_b[f*4+2][c] = v.z; lds_b[f*4+3][c] = v.w;
        }
        __syncthreads();
        #pragma unroll
        for (int j = 0; j < BKg; ++j) {
            float4 a4 = *(const float4*)&lds_a[j][ty*4];
            float4 b4 = *(const float4*)&lds_b[j][tx*4];
            float a[4] = {a4.x, a4.y, a4.z, a4.w};
            float b[4] = {b4.x, b4.y, b4.z, b4.w};
            #pragma unroll
            for (int i = 0; i < 4; ++i)
                #pragma unroll
                for (int jj = 0; jj < 4; ++jj)
                    acc[i][jj] += a[i] * b[jj];
        }
        __syncthreads();
    }

    #pragma unroll
    for (int i = 0; i < 4; ++i) {
        int r = row0 + ty*4 + i;
        float vals[4];
        #pragma unroll
        for (int j = 0; j < 4; ++j) {
            float v = acc[i][j] + bias[col0 + tx*4 + j];
            vals[j] = (ACT == 1) ? elu_act(v) : v;
        }
        *(float4*)(dst + (size_t)r * N + col0 + tx*4) =
            make_float4(vals[0], vals[1], vals[2], vals[3]);
    }
}

// ===========================================================================
// Gating layer 3 + softmax (fp32)
// ===========================================================================
__global__ __launch_bounds__(256)
void gating3_softmax(const float* __restrict__ g2, const float* __restrict__ Wg3,
                     const float* __restrict__ bg3, float* __restrict__ bc)
{
    __shared__ float w[NEXP * GH];
    __shared__ float bsh[NEXP];
    const int tid = threadIdx.x;
    for (int i = tid; i < NEXP * GH; i += 256) w[i] = Wg3[i];
    if (tid < NEXP) bsh[tid] = bg3[tid];
    __syncthreads();

    const int rowl = tid >> 3;
    const int o    = tid & 7;
    const int row  = blockIdx.x * 32 + rowl;
    const float* g = g2 + (size_t)row * GH;

    float s = bsh[o];
    for (int k = 0; k < GH; ++k) s += g[k] * w[o * GH + k];

    float m = s;
    #pragma unroll
    for (int d = 4; d >= 1; d >>= 1) m = fmaxf(m, __shfl_xor(m, d, 8));
    float e = expf(s - m);
    float sum = e;
    #pragma unroll
    for (int d = 4; d >= 1; d >>= 1) sum += __shfl_xor(sum, d, 8);

    bc[(size_t)blockIdx.x * 256 + tid] = e / sum;
}

// ===========================================================================
// Helper kernels
// ===========================================================================
// Fill z-columns (1024..1087) of both hz buffers with f16(z) (unscaled).
__global__ __launch_bounds__(256)
void fill_z(const float* __restrict__ z, f16* __restrict__ hz_a,
            f16* __restrict__ hz_b)
{
    int i = (blockIdx.x * 256 + threadIdx.x) * 4;      // over 4096*64
    int row = i >> 6;
    int col = i & 63;
    float4 v = *(const float4*)(z + i);
    f16x4 o = { (f16)v.x, (f16)v.y, (f16)v.z, (f16)v.w };
    size_t off = (size_t)row * (HDIM + ZDIM) + HDIM + col;
    *(f16x4*)(hz_a + off) = o;
    *(f16x4*)(hz_b + off) = o;
}

// fp32 -> f16 weight conversion, 8 elements/thread
__global__ __launch_bounds__(256)
void w_to_f16(const float* __restrict__ src, f16* __restrict__ dst)
{
    size_t i = ((size_t)blockIdx.x * 256 + threadIdx.x) * 8;
    float4 v0 = *(const float4*)(src + i);
    float4 v1 = *(const float4*)(src + i + 4);
    f16x8 o = { (f16)v0.x,(f16)v0.y,(f16)v0.z,(f16)v0.w,
                (f16)v1.x,(f16)v1.y,(f16)v1.z,(f16)v1.w };
    *(f16x8*)(dst + i) = o;
}

// ===========================================================================
// Blended expert layer, "big-K" formulation:
//   out[b,o] = act( sum_e (bc[b,e]*A[b,:]) . Wf[e,o,:] + sum_e bc[b,e]*bias[e,o] )
//
// v6 (resubmit #2 — rounds 5 and 6 hit infra container failures, never ran)
// = v5 (wave 64m x 32n, ~105 live VGPRs, no spill) + REGISTER-PIPELINED
// expert loop. v1/v2/v5 all measured the same 7566-cyc window despite 1.7x
// different LDS traffic and 2x different wave count -> bottleneck is the
// latency-serialized  ds_read bf -> lgkmcnt(0) -> MFMA  chain per expert
// (8 x ~120cyc exposed LDS latency + shared-pipe time ~= 7.5k cyc).
// Fix: rotate bf reads one expert ahead (base + const-offset ds_reads;
// compiler emits counted lgkmcnt instead of a full wait). +8 VGPRs.
// Bounds audit: max ds_read offset = 7*4096 + 3576 + 512 + 8 = 32768 f16
// = exactly b_sh[cur] size -> in bounds.
// ===========================================================================
template<int KE, int N, int ACT, int SRC, typename OT>
__global__ __launch_bounds__(512)
__attribute__((amdgpu_waves_per_eu(2)))
void blended_big(const f16* __restrict__ A, int ldA,
                 const float* __restrict__ x, const float* __restrict__ z,
                 const f16* __restrict__ Wf, const float* __restrict__ bias,
                 const float* __restrict__ bc, OT* __restrict__ out, int ldOut)
{
    constexpr int NCT = N / 128;
    constexpr int NW  = KE / 32;
    __shared__ __align__(16) f16 b_sh[2][NEXP * 128 * 32];   // 128 KB, glds dest
    __shared__ __align__(16) f16 a_sh[2][128][40];           // 20 KB, pad 40
    __shared__ float bc_sh[128][8];
    __shared__ float bias_sh[8][128];

    const int tid  = threadIdx.x;
    const int bid  = blockIdx.x;
    const int row0 = (bid / NCT) * 128;
    const int col0 = (bid % NCT) * 128;  // % NCT aligns col-slice with XCD L2
    const int wave = tid >> 6;
    const int lane = tid & 63;
    const int ln   = lane & 15;
    const int quad = lane >> 4;
    const int bhalf = wave >> 2;          // 0..1 : rows [bhalf*64, +64)
    const int ocol  = wave & 3;           // 0..3 : cols [ocol*32, +32)

    // one-time staging of bc and bias tiles (for the epilogue)
    for (int i = tid; i < 128 * 8; i += 512)
        bc_sh[i >> 3][i & 7] = bc[(size_t)(row0 + (i >> 3)) * NEXP + (i & 7)];
    for (int i = tid; i < 8 * 128; i += 512)
        bias_sh[i >> 7][i & 127] = bias[(size_t)(i >> 7) * N + col0 + (i & 127)];

    // per-lane bc scale factors for A-frag rows (m = bhalf*64 + mi*16 + ln),
    // PACKED: bcfv[mi][e]. 4x f16x8 = 16 VGPRs.
    f16x8 bcfv[4];
    #pragma unroll
    for (int mi = 0; mi < 4; ++mi) {
        const float* bp = bc + (size_t)(row0 + bhalf*64 + mi*16 + ln) * NEXP;
        float4 c0 = *(const float4*)bp;
        float4 c1 = *(const float4*)(bp + 4);
        bcfv[mi] = (f16x8){ (f16)c0.x,(f16)c0.y,(f16)c0.z,(f16)c0.w,
                            (f16)c1.x,(f16)c1.y,(f16)c1.z,(f16)c1.w };
    }

    // A staging coords: thread -> (row 0..127, k-chunk 0..3)
    const int ar = tid >> 2;
    const int ac = tid & 3;
    // B staging lane constants (XOR-swizzled k-chunks):
    // chunk j*64+lane -> p=j*16+(lane>>2), stored kc = (lane&3)^((lane>>3)&3)
    const int kcl  = (lane & 3) ^ ((lane >> 3) & 3);
    const int prow = lane >> 2;           // 0..15
    // per-wave: stage expert e = wave (8 waves <-> 8 experts)
    const f16* wb = Wf + ((size_t)wave * N + col0 + prow) * KE + kcl * 8;
    // B frag-read lane constant: stored chunk for global chunk q=quad of row n
    const int csel = quad ^ ((ln >> 1) & 3);

    f32x4 acc[4][2] = {};

    float4 sv0, sv1;   // SRC==0 in-flight A staging regs
    f16x8  sa;         // SRC==1 in-flight A staging regs

    auto stage_issue = [&](int buf, int k0) {
        // A global loads FIRST (their waitcnt then leaves B glds in flight)
        if (SRC == 0) {
            int k = k0 + ac * 8;   // 800 % 8 == 0: chunk is pure-x or pure-z
            const float* s = (k < XDIM)
                ? x + (size_t)(row0 + ar) * XDIM + k
                : z + (size_t)(row0 + ar) * ZDIM + (k - XDIM);
            sv0 = *(const float4*)s;
            sv1 = *(const float4*)(s + 4);
        } else {
            sa = *(const f16x8*)(A + (size_t)(row0 + ar) * ldA + k0 + ac * 8);
        }
        // B tile: expert 'wave', 128x32 f16 via 8 glds16/thread (async)
        #pragma unroll
        for (int j = 0; j < 8; ++j)
            glds16(wb + k0 + (size_t)j * 16 * KE,
                   &b_sh[buf][(wave * 128 + j * 16) * 32]);
    };
    auto stage_commit = [&](int buf) {
        f16x8 av;
        if (SRC == 0) {
            av = (f16x8){ (f16)sv0.x,(f16)sv0.y,(f16)sv0.z,(f16)sv0.w,
                          (f16)sv1.x,(f16)sv1.y,(f16)sv1.z,(f16)sv1.w };
        } else {
            av = sa;
        }
        *(f16x8*)&a_sh[buf][ar][ac * 8] = av;
    };

    // prologue: fill buffer 0
    stage_issue(0, 0);
    stage_commit(0);
    __syncthreads();   // also covers bc_sh/bias_sh

    int cur = 0;
    for (int t = 0; t < NW; ++t) {
        const bool pf = (t + 1 < NW);
        if (pf) stage_issue(cur ^ 1, (t + 1) * 32);   // prefetch next window

        // A frags: 64-row half, reused across all 8 experts (and 2 n-tiles)
        f16x8 af[4];
        #pragma unroll
        for (int mi = 0; mi < 4; ++mi)
            af[mi] = *(const f16x8*)&a_sh[cur][bhalf*64 + mi*16 + ln][quad * 8];

        // expert loop, software-pipelined: prefetch e+1's B frags (base +
        // constant offsets: e stride 4096, nj stride 512) during e's MFMAs.
        const f16* bbase = &b_sh[cur][(ocol*32 + ln) * 32 + csel * 8];
        f16x8 nb0 = *(const f16x8*)(bbase);
        f16x8 nb1 = *(const f16x8*)(bbase + 512);

        __builtin_amdgcn_s_setprio(1);
        #pragma unroll
        for (int e = 0; e < NEXP; ++e) {
            f16x8 cb0 = nb0, cb1 = nb1;
            if (e + 1 < NEXP) {
                nb0 = *(const f16x8*)(bbase + (e + 1) * 4096);
                nb1 = *(const f16x8*)(bbase + (e + 1) * 4096 + 512);
            }
            #pragma unroll
            for (int mi = 0; mi < 4; ++mi) {
                f16x8 as = vscale(af[mi], bcfv[mi][e]);
                acc[mi][0] = __builtin_amdgcn_mfma_f32_16x16x32_f16(
                    as, cb0, acc[mi][0], 0, 0, 0);
                acc[mi][1] = __builtin_amdgcn_mfma_f32_16x16x32_f16(
                    as, cb1, acc[mi][1], 0, 0, 0);
            }
        }
        __builtin_amdgcn_s_setprio(0);

        if (pf) stage_commit(cur ^ 1);   // A write after compute
        __syncthreads();                 // single barrier per window (dbuf)
        cur ^= 1;
    }

    // epilogue: + sum_e bc*bias, activation, store
    #pragma unroll
    for (int mi = 0; mi < 4; ++mi) {
        #pragma unroll
        for (int r = 0; r < 4; ++r) {
            int rl = bhalf*64 + mi*16 + quad*4 + r;
            size_t grow = (size_t)(row0 + rl) * ldOut;
            #pragma unroll
            for (int nj = 0; nj < 2; ++nj) {
                int cl = ocol*32 + nj*16 + ln;
                float v = acc[mi][nj][r];
                #pragma unroll
                for (int e2 = 0; e2 < NEXP; ++e2)
                    v += bc_sh[rl][e2] * bias_sh[e2][cl];
                if (ACT) v = elu_act(v);
                out[grow + col0 + cl] = (OT)v;
            }
        }
    }
}

// ===========================================================================
extern "C" void kernel_launch(void* const* d_in, const int* in_sizes, int n_in,
                              void* d_out, int out_size, void* d_ws, size_t ws_size,
                              hipStream_t stream)
{
    const float* x   = (const float*)d_in[0];
    const float* z   = (const float*)d_in[1];
    const float* Wg1 = (const float*)d_in[2];
    const float* bg1 = (const float*)d_in[3];
    const float* Wg2 = (const float*)d_in[4];
    const float* bg2 = (const float*)d_in[5];
    const float* Wg3 = (const float*)d_in[6];
    const float* bg3 = (const float*)d_in[7];
    const float* W0  = (const float*)d_in[8];
    const float* b0  = (const float*)d_in[9];
    const float* W1  = (const float*)d_in[10];
    const float* b1  = (const float*)d_in[11];
    const float* W2  = (const float*)d_in[12];
    const float* b2  = (const float*)d_in[13];
    const float* W3  = (const float*)d_in[14];
    const float* b3  = (const float*)d_in[15];
    float* out = (float*)d_out;

    // workspace (~40 MB): wbuf f16 [8*1024*1088], hz_a/hz_b f16 [4096][1088],
    // g1/g2 f32 [4096][128], bc f32 [4096][8]
    char* ws = (char*)d_ws;
    f16*   wbuf = (f16*)ws;                 ws += (size_t)NEXP * HDIM * (HDIM + ZDIM) * 2;
    f16*   hz_a = (f16*)ws;                 ws += (size_t)BDIM * (HDIM + ZDIM) * 2;
    f16*   hz_b = (f16*)ws;                 ws += (size_t)BDIM * (HDIM + ZDIM) * 2;
    float* g1   = (float*)ws;               ws += (size_t)BDIM * GH * 4;
    float* g2   = (float*)ws;               ws += (size_t)BDIM * GH * 4;
    float* bcw  = (float*)ws;

    dim3 blk(256);
    dim3 blk512(512);

    // z-columns of hz buffers
    fill_z<<<dim3(BDIM * ZDIM / 4 / 256), blk, 0, stream>>>(z, hz_a, hz_b);

    // gating MLP (fp32)
    gemm_cat<1><<<dim3(BDIM/BMg, GH/BNg), blk, 0, stream>>>(x, XDIM, z, ZDIM, Wg1, bg1, g1, GH);
    gemm_cat<1><<<dim3(BDIM/BMg, GH/BNg), blk, 0, stream>>>(g1, GH, nullptr, 0, Wg2, bg2, g2, GH);
    gating3_softmax<<<dim3(BDIM/32), blk, 0, stream>>>(g2, Wg3, bg3, bcw);

    // blended expert layers: convert weights to f16, then big-K MFMA GEMM
    // grid = (4096/128) x (N/128) blocks of 512 threads
    w_to_f16<<<dim3(NEXP*HDIM*(XDIM+ZDIM)/8/256), blk, 0, stream>>>(W0, wbuf);
    blended_big<XDIM+ZDIM, HDIM, 1, 0, f16><<<dim3(32 * 8), blk512, 0, stream>>>(
        nullptr, 0, x, z, wbuf, b0, bcw, hz_a, HDIM + ZDIM);

    w_to_f16<<<dim3(NEXP*HDIM*(HDIM+ZDIM)/8/256), blk, 0, stream>>>(W1, wbuf);
    blended_big<HDIM+ZDIM, HDIM, 1, 1, f16><<<dim3(32 * 8), blk512, 0, stream>>>(
        hz_a, HDIM + ZDIM, nullptr, nullptr, wbuf, b1, bcw, hz_b, HDIM + ZDIM);

    w_to_f16<<<dim3(NEXP*HDIM*(HDIM+ZDIM)/8/256), blk, 0, stream>>>(W2, wbuf);
    blended_big<HDIM+ZDIM, HDIM, 1, 1, f16><<<dim3(32 * 8), blk512, 0, stream>>>(
        hz_b, HDIM + ZDIM, nullptr, nullptr, wbuf, b2, bcw, hz_a, HDIM + ZDIM);

    w_to_f16<<<dim3(NEXP*ODIM*HDIM/8/256), blk, 0, stream>>>(W3, wbuf);
    blended_big<HDIM, ODIM, 0, 1, float><<<dim3(32 * 6), blk512, 0, stream>>>(
        hz_a, HDIM + ZDIM, nullptr, nullptr, wbuf, b3, bcw, out, ODIM);
}